// Round 1
// 920.337 us; speedup vs baseline: 1.0391x; 1.0391x over previous
//
#include <hip/hip_runtime.h>
#include <math.h>

#define NN 8192

typedef __attribute__((ext_vector_type(8))) short short8;
typedef __attribute__((ext_vector_type(4))) float f32x4;

__device__ __forceinline__ float bf2f(unsigned short u) {
    unsigned int x = ((unsigned int)u) << 16;
    return __builtin_bit_cast(float, x);
}
__device__ __forceinline__ unsigned int cvt_pk_bf16(float lo, float hi) {
    unsigned int r;
    asm("v_cvt_pk_bf16_f32 %0, %1, %2" : "=v"(r) : "v"(lo), "v"(hi));
    return r;
}
__device__ __forceinline__ float fast_sigexp(float x) {
    float s = __builtin_amdgcn_rcpf(1.0f + __expf(-x));
    return __expf(s);
}
__device__ __forceinline__ void gload16(const void* g, void* l) {
    __builtin_amdgcn_global_load_lds(
        (const __attribute__((address_space(1))) unsigned int*)g,
        (__attribute__((address_space(3))) unsigned int*)l, 16, 0, 0);
}

// ---------------- fp32 -> bf16 conversion ----------------
__global__ __launch_bounds__(256) void cvt_bf16(
    const float* __restrict__ src, unsigned short* __restrict__ dst)
{
    size_t idx = ((size_t)blockIdx.x * 256 + threadIdx.x) * 8;
    float4 a = *(const float4*)(src + idx);
    float4 b = *(const float4*)(src + idx + 4);
    uint4 o = { cvt_pk_bf16(a.x, a.y), cvt_pk_bf16(a.z, a.w),
                cvt_pk_bf16(b.x, b.y), cvt_pk_bf16(b.z, b.w) };
    *(uint4*)(dst + idx) = o;
}

// ---------------- raw 32B row loads + conversion helpers ----------------
template<typename AT> struct ARow;
template<> struct ARow<unsigned short> {
    struct Raw { uint4 a, b; };
    static __device__ __forceinline__ Raw ld(const unsigned short* p) {
        Raw r; r.a = ((const uint4*)p)[0]; r.b = ((const uint4*)p)[1]; return r;
    }
    static __device__ __forceinline__ void cvt(const Raw& r, float* d) {
        unsigned int wd[8] = {r.a.x, r.a.y, r.a.z, r.a.w, r.b.x, r.b.y, r.b.z, r.b.w};
        #pragma unroll
        for (int k = 0; k < 8; ++k) {
            d[2*k]   = __builtin_bit_cast(float, wd[k] << 16);
            d[2*k+1] = __builtin_bit_cast(float, wd[k] & 0xFFFF0000u);
        }
    }
};
template<> struct ARow<float> {
    struct Raw { float4 v[4]; };
    static __device__ __forceinline__ Raw ld(const float* p) {
        Raw r;
        r.v[0] = ((const float4*)p)[0]; r.v[1] = ((const float4*)p)[1];
        r.v[2] = ((const float4*)p)[2]; r.v[3] = ((const float4*)p)[3];
        return r;
    }
    static __device__ __forceinline__ void cvt(const Raw& r, float* d) {
        #pragma unroll
        for (int q = 0; q < 4; ++q) {
            d[4*q+0] = r.v[q].x; d[4*q+1] = r.v[q].y;
            d[4*q+2] = r.v[q].z; d[4*q+3] = r.v[q].w;
        }
    }
};
// f32 fallback staging of one 16-elem A-col chunk into bf16 LDS
struct AcStageF32 {
    static __device__ __forceinline__ void st(const ARow<float>::Raw& rw, unsigned short* dst) {
        float v[16];
        ARow<float>::cvt(rw, v);
        unsigned int d[8];
        #pragma unroll
        for (int k = 0; k < 8; ++k) d[k] = cvt_pk_bf16(v[2*k], v[2*k+1]);
        uint4 s0 = {d[0], d[1], d[2], d[3]};
        uint4 s1 = {d[4], d[5], d[6], d[7]};
        ((uint4*)dst)[0] = s0;
        ((uint4*)dst)[1] = s1;
    }
};

// ---------------- projection GEMM (bf16 MFMA): Zt[o][i] = relu(H@W^T + b) ----------------
// double-buffered LDS, prefetch-at-top, ONE barrier per K-step (latency hidden 1 deep)
__global__ __launch_bounds__(256) void proj_mfma(
    const unsigned short* __restrict__ Hbf,
    const unsigned short* __restrict__ Wbf,
    const float* __restrict__ bias,
    unsigned short* __restrict__ Zt,
    int K, int O)
{
    constexpr int MT = 4, NT = 2;
    __shared__ unsigned short smem[12288];   // 2 bufs x (As 4096 + Bs 2048) shorts
    const int tid = threadIdx.x;
    const int w = tid >> 6;
    const int lane = tid & 63;
    const int quad = lane >> 4;
    const int m16 = lane & 15;
    const int i0 = blockIdx.y * 128;
    const int o0 = blockIdx.x * 64;
    const int wm = w & 1;
    const int wn = w >> 1;

    const char* gpa[2]; unsigned int loa[2];
    #pragma unroll
    for (int n = 0; n < 2; ++n) {
        int o16 = n * 256 + w * 64 + lane;
        int row = o16 >> 2, ch = o16 & 3;
        int sc = ch ^ ((row >> 1) & 3);
        gpa[n] = (const char*)(Hbf + (size_t)(i0 + row) * K) + sc * 16;
        loa[n] = n * 4096 + w * 1024 + lane * 16;
    }
    const char* gpb; unsigned int lob_;
    {
        int o16 = w * 64 + lane;
        int row = o16 >> 2, ch = o16 & 3;
        int sc = ch ^ ((row >> 1) & 3);
        gpb = (const char*)(Wbf + (size_t)(o0 + row) * K) + sc * 16;
        lob_ = 8192 + w * 1024 + lane * 16;   // Bs region at byte 8192 of buffer
    }
    int aoff[MT], boff[NT];
    #pragma unroll
    for (int mt = 0; mt < MT; ++mt) {
        int row = wm * 64 + mt * 16 + m16;
        int sc = quad ^ ((row >> 1) & 3);
        aoff[mt] = row * 32 + sc * 8;
    }
    #pragma unroll
    for (int nt = 0; nt < NT; ++nt) {
        int row = wn * 32 + nt * 16 + m16;
        int sc = quad ^ ((row >> 1) & 3);
        boff[nt] = 4096 + row * 32 + sc * 8;
    }
    f32x4 acc[MT][NT];
    #pragma unroll
    for (int mt = 0; mt < MT; ++mt)
        #pragma unroll
        for (int nt = 0; nt < NT; ++nt)
            acc[mt][nt] = (f32x4){0.f, 0.f, 0.f, 0.f};

    // prologue: stage k-block 0 into buf 0
    gload16(gpa[0], (char*)smem + loa[0]);
    gload16(gpa[1], (char*)smem + loa[1]);
    gload16(gpb,    (char*)smem + lob_);
    __syncthreads();

    const int nk = K >> 5;
    for (int kk = 0; kk < nk; ++kk) {
        const int s = kk & 1;
        if (kk + 1 < nk) {
            char* dst = (char*)smem + (s ^ 1) * 12288;
            gload16(gpa[0] + (size_t)(kk + 1) * 64, dst + loa[0]);
            gload16(gpa[1] + (size_t)(kk + 1) * 64, dst + loa[1]);
            gload16(gpb    + (size_t)(kk + 1) * 64, dst + lob_);
        }
        const unsigned short* buf = smem + s * 6144;
        short8 af[MT], bf_[NT];
        #pragma unroll
        for (int mt = 0; mt < MT; ++mt) af[mt] = *(const short8*)(buf + aoff[mt]);
        #pragma unroll
        for (int nt = 0; nt < NT; ++nt) bf_[nt] = *(const short8*)(buf + boff[nt]);
        #pragma unroll
        for (int mt = 0; mt < MT; ++mt)
            #pragma unroll
            for (int nt = 0; nt < NT; ++nt)
                acc[mt][nt] = __builtin_amdgcn_mfma_f32_16x16x32_bf16(
                    af[mt], bf_[nt], acc[mt][nt], 0, 0, 0);
        __syncthreads();   // drains next-buf gloads; guards read-before-overwrite
    }
    #pragma unroll
    for (int nt = 0; nt < NT; ++nt) {
        int ol = wn * 32 + nt * 16 + m16;
        float bv = bias[o0 + ol];
        #pragma unroll
        for (int mt = 0; mt < MT; ++mt) {
            int il = wm * 64 + mt * 16 + quad * 4;
            float f0 = fmaxf(acc[mt][nt][0] + bv, 0.f);
            float f1 = fmaxf(acc[mt][nt][1] + bv, 0.f);
            float f2 = fmaxf(acc[mt][nt][2] + bv, 0.f);
            float f3 = fmaxf(acc[mt][nt][3] + bv, 0.f);
            uint2 pk = { cvt_pk_bf16(f0, f1), cvt_pk_bf16(f2, f3) };
            *(uint2*)&smem[ol * 136 + il] = pk;
        }
    }
    __syncthreads();
    #pragma unroll
    for (int c = 0; c < 4; ++c) {
        int cc = c * 256 + tid;
        int ol = cc >> 4;
        int ic = (cc & 15) << 3;
        *(uint4*)(Zt + (size_t)(o0 + ol) * NN + i0 + ic) = *(const uint4*)&smem[ol * 136 + ic];
    }
}

// ---------------- t,r: column-split atomic dots over Zt ----------------
__global__ __launch_bounds__(256) void tr_zt(
    const unsigned short* __restrict__ Zt,
    const float* __restrict__ tw, const float* __restrict__ tb,
    const float* __restrict__ rw, const float* __restrict__ rb,
    float* __restrict__ t, float* __restrict__ r)
{
    const int i  = blockIdx.x * 256 + threadIdx.x;
    const int c0 = blockIdx.y * 64;
    float at = 0.f, ar = 0.f;
    for (int c = c0; c < c0 + 64; ++c) {
        float z = bf2f(Zt[(size_t)c * NN + i]);
        at = fmaf(z, tw[c], at);
        ar = fmaf(z, rw[c], ar);
    }
    if (blockIdx.y == 0) { at += tb[0]; ar += rb[0]; }
    atomicAdd(t + i, at);
    atomicAdd(r + i, ar);
}

// ---------------- fused attention: P on the fly + bf16 MFMA + denom ----------------
// Pipeline per K-step:
//   [issue gload16 prefetch (Bs[b^1], Ac[b^1]) for kk+1]   <- latency covered by P-phase
//   [P compute from Ac[b]/avr/tvr -> As]
//   barrier A (vmcnt drain now covered)
//   [load avr/tvr(kk+1) regs; f32-path Ac write]            <- covered by MFMA phase
//   [MFMA As x Bs[b]]
//   barrier B
// Ac is double-buffered, staged gload16-direct (bf16 path), conflict-free via
// chunk swizzle: source chunk ^ ((row>>4)<<2), read column ci ^ (jh<<5).
template<int BN, typename AT>
__global__ __launch_bounds__(256) void attn_fused(
    const AT* __restrict__ A,
    const unsigned short* __restrict__ Zt,   // [O][NN] bf16
    const float* __restrict__ t, const float* __restrict__ r,
    float* __restrict__ Hacc, float* __restrict__ denom,
    int O, int kcount)
{
    constexpr bool BFA = (sizeof(AT) == 2);
    constexpr int BM = 128, BK = 32;
    constexpr int MT = 4;
    constexpr int NT = BN / 32;
    constexpr int NB = (BN * BK * 2) / 4096;
    constexpr int BNK = BN * BK;
    __shared__ unsigned short As[BM * BK];       // P tile (single-buffered)
    __shared__ unsigned short Bs[2][BNK];        // Zt tiles (double-buffered)
    __shared__ unsigned short Ac[2][BK * BM];    // A-col tiles [j][i], stride 128, dbuf
    const int tid  = threadIdx.x;
    const int w    = tid >> 6;
    const int lane = tid & 63;
    const int quad = lane >> 4;
    const int m16  = lane & 15;
    const int i0 = blockIdx.y * BM;
    const int c0 = blockIdx.x * BN;
    const int wm = w & 1;
    const int wn = w >> 1;
    const int jbase = blockIdx.z * kcount * BK;

    // compute-role: thread owns (row ci, 16-j half jh)
    const int ci = tid >> 1;
    const int jh = tid & 1;
    const float ri = r[i0 + ci];
    const int si = (ci >> 1) & 3;
    unsigned short* asw0 = As + ci * 32 + (((jh * 2)    ) ^ si) * 8;
    unsigned short* asw1 = As + ci * 32 + (((jh * 2) + 1) ^ si) * 8;
    const int acrd = jh * 16 * BM + (ci ^ (jh << 5));   // swizzled Ac read base

    // Bs gload pointers
    const char* gpb[NB]; unsigned int lob[NB];
    #pragma unroll
    for (int n = 0; n < NB; ++n) {
        int o16 = n * 256 + w * 64 + lane;
        int row = o16 >> 2, ch = o16 & 3;
        int sc = ch ^ ((row >> 1) & 3);
        gpb[n] = (const char*)Zt + ((size_t)(c0 + row) * NN + jbase) * 2 + sc * 16;
        lob[n] = n * 4096 + w * 1024 + lane * 16;
    }
    // Ac staging: gload16-direct (bf16) or reg-staged (f32 fallback)
    const char* gpac[2] = {nullptr, nullptr};
    unsigned int loac[2] = {0, 0};
    const float* astage = nullptr;
    int acw_off = 0;
    if constexpr (BFA) {
        #pragma unroll
        for (int n = 0; n < 2; ++n) {
            int o16 = n * 256 + tid;
            int row = o16 >> 4;
            int c16 = (o16 & 15) ^ ((row >> 4) << 2);   // pre-swizzled global source
            gpac[n] = (const char*)(A + (size_t)(jbase + row) * NN + i0 + c16 * 8);
            loac[n] = (unsigned int)(o16 * 16);
        }
    } else {
        const int sj = tid >> 3;
        const int sm = tid & 7;
        astage = (const float*)A + (size_t)(jbase + sj) * NN + i0 + sm * 16;
        acw_off = sj * BM + (((sm * 2) ^ ((sj >> 4) << 2)) * 8);
    }

    int aoff[MT], boff[NT];
    #pragma unroll
    for (int mt = 0; mt < MT; ++mt) {
        int row = wm * 64 + mt * 16 + m16;
        int sc = quad ^ ((row >> 1) & 3);
        aoff[mt] = row * 32 + sc * 8;
    }
    #pragma unroll
    for (int nt = 0; nt < NT; ++nt) {
        int row = wn * (BN / 2) + nt * 16 + m16;
        int sc = quad ^ ((row >> 1) & 3);
        boff[nt] = row * 32 + sc * 8;
    }

    f32x4 acc[MT][NT];
    #pragma unroll
    for (int mt = 0; mt < MT; ++mt)
        #pragma unroll
        for (int nt = 0; nt < NT; ++nt)
            acc[mt][nt] = (f32x4){0.f, 0.f, 0.f, 0.f};

    const AT* arow = A + (size_t)(i0 + ci) * NN + jbase + jh * 16;
    const float* tptr = t + jbase + jh * 16;

    // prologue: stage j-block 0
    #pragma unroll
    for (int n = 0; n < NB; ++n)
        gload16(gpb[n], (char*)(Bs[0]) + lob[n]);
    if constexpr (BFA) {
        gload16(gpac[0], (char*)(Ac[0]) + loac[0]);
        gload16(gpac[1], (char*)(Ac[0]) + loac[1]);
    } else {
        ARow<float>::Raw a0 = ARow<float>::ld(astage);
        AcStageF32::st(a0, &Ac[0][0] + acw_off);
    }
    typename ARow<AT>::Raw avr = ARow<AT>::ld(arow);
    float4 tvr0 = ((const float4*)tptr)[0];
    float4 tvr1 = ((const float4*)tptr)[1];
    float4 tvr2 = ((const float4*)tptr)[2];
    float4 tvr3 = ((const float4*)tptr)[3];
    __syncthreads();

    ARow<float>::Raw acr;   // f32-path only (dead in bf16 instantiation)
    float rsum = 0.f;
    for (int kk = 0; kk < kcount; ++kk) {
        const int b = kk & 1;
        // ---- prefetch issues for kk+1 (covered by P-phase below) ----
        if (kk + 1 < kcount) {
            #pragma unroll
            for (int n = 0; n < NB; ++n)
                gload16(gpb[n] + (size_t)(kk + 1) * 64, (char*)(Bs[b ^ 1]) + lob[n]);
            if constexpr (BFA) {
                gload16(gpac[0] + (size_t)(kk + 1) * (BK * NN * 2), (char*)(Ac[b ^ 1]) + loac[0]);
                gload16(gpac[1] + (size_t)(kk + 1) * (BK * NN * 2), (char*)(Ac[b ^ 1]) + loac[1]);
            } else {
                acr = ARow<float>::ld(astage + (size_t)(kk + 1) * BK * NN);
            }
        }
        // ---- P compute phase: p -> As (reads Ac[b] + regs) ----
        float av[16];
        ARow<AT>::cvt(avr, av);
        float tf[16] = {tvr0.x, tvr0.y, tvr0.z, tvr0.w,
                        tvr1.x, tvr1.y, tvr1.z, tvr1.w,
                        tvr2.x, tvr2.y, tvr2.z, tvr2.w,
                        tvr3.x, tvr3.y, tvr3.z, tvr3.w};
        const unsigned short* acb = &Ac[b][0] + acrd;
        unsigned int wd[8];
        #pragma unroll
        for (int q = 0; q < 8; ++q) {
            float j0 = bf2f(acb[(2 * q) * BM]);
            float j1 = bf2f(acb[(2 * q + 1) * BM]);
            float x0 = fmaf(av[2 * q],     tf[2 * q],     j0 * ri);
            float x1 = fmaf(av[2 * q + 1], tf[2 * q + 1], j1 * ri);
            float p0 = fast_sigexp(x0);
            float p1 = fast_sigexp(x1);
            rsum += p0; rsum += p1;
            wd[q] = cvt_pk_bf16(p0, p1);
        }
        {
            uint4 s0 = {wd[0], wd[1], wd[2], wd[3]};
            uint4 s1 = {wd[4], wd[5], wd[6], wd[7]};
            *(uint4*)asw0 = s0;
            *(uint4*)asw1 = s1;
        }
        __syncthreads();   // barrier A: As ready; prefetch vmcnt drain covered by P-phase
        // ---- next-iteration register loads (covered by MFMA phase) ----
        if (kk + 1 < kcount) {
            avr = ARow<AT>::ld(arow + (size_t)(kk + 1) * BK);
            const float* tp = tptr + (kk + 1) * BK;
            tvr0 = ((const float4*)tp)[0];
            tvr1 = ((const float4*)tp)[1];
            tvr2 = ((const float4*)tp)[2];
            tvr3 = ((const float4*)tp)[3];
            if constexpr (!BFA)
                AcStageF32::st(acr, &Ac[b ^ 1][0] + acw_off);
        }
        // ---- MFMA phase ----
        {
            const unsigned short* bsb = Bs[b];
            short8 af[MT], bf_[NT];
            #pragma unroll
            for (int mt = 0; mt < MT; ++mt) af[mt] = *(const short8*)(As + aoff[mt]);
            #pragma unroll
            for (int nt = 0; nt < NT; ++nt) bf_[nt] = *(const short8*)(bsb + boff[nt]);
            #pragma unroll
            for (int mt = 0; mt < MT; ++mt)
                #pragma unroll
                for (int nt = 0; nt < NT; ++nt)
                    acc[mt][nt] = __builtin_amdgcn_mfma_f32_16x16x32_bf16(
                        af[mt], bf_[nt], acc[mt][nt], 0, 0, 0);
        }
        __syncthreads();   // barrier B: As/Bs[b] reads done before overwrite
    }

    // denom accumulation (unquantized fp32 row sums), x==0 blocks only
    rsum += __shfl_xor(rsum, 1);
    if (jh == 0 && blockIdx.x == 0)
        atomicAdd(denom + i0 + ci, rsum);

    // unnormalized atomic output
    const int colb = c0 + wn * (BN / 2) + m16;
    #pragma unroll
    for (int mt = 0; mt < MT; ++mt) {
        int rowb = i0 + wm * 64 + mt * 16 + quad * 4;
        #pragma unroll
        for (int rg = 0; rg < 4; ++rg) {
            float* orow = Hacc + (size_t)(rowb + rg) * O + colb;
            #pragma unroll
            for (int nt = 0; nt < NT; ++nt)
                atomicAdd(orow + nt * 16, acc[mt][nt][rg]);
        }
    }
}

// ---------------- normalize + emit (f32 out or bf16 next-layer input) ----------------
__global__ __launch_bounds__(256) void norm_cvt(
    const float* __restrict__ Hacc, const float* __restrict__ denom,
    float* __restrict__ outf, unsigned short* __restrict__ outb, int O)
{
    const int gid = blockIdx.x * 256 + threadIdx.x;
    const int n4 = O >> 2;
    const int i = gid / n4;
    const int c = (gid % n4) << 2;
    float inv = __builtin_amdgcn_rcpf(denom[i]);
    float4 v = *(const float4*)(Hacc + (size_t)i * O + c);
    v.x *= inv; v.y *= inv; v.z *= inv; v.w *= inv;
    if (outf) {
        *(float4*)(outf + (size_t)i * O + c) = v;
    } else {
        uint2 o = { cvt_pk_bf16(v.x, v.y), cvt_pk_bf16(v.z, v.w) };
        *(uint2*)(outb + (size_t)i * O + c) = o;
    }
}

// ---------------- host ----------------
extern "C" void kernel_launch(void* const* d_in, const int* in_sizes, int n_in,
                              void* d_out, int out_size, void* d_ws, size_t ws_size,
                              hipStream_t stream)
{
    (void)in_sizes; (void)n_in; (void)out_size;
    const float* X = (const float*)d_in[0];
    const float* A = (const float*)d_in[1];
    const float* Wws[3] = {(const float*)d_in[2],  (const float*)d_in[8],  (const float*)d_in[14]};
    const float* Wbs[3] = {(const float*)d_in[3],  (const float*)d_in[9],  (const float*)d_in[15]};
    const float* tws[3] = {(const float*)d_in[4],  (const float*)d_in[10], (const float*)d_in[16]};
    const float* tbs[3] = {(const float*)d_in[5],  (const float*)d_in[11], (const float*)d_in[17]};
    const float* rws[3] = {(const float*)d_in[6],  (const float*)d_in[12], (const float*)d_in[18]};
    const float* rbs[3] = {(const float*)d_in[7],  (const float*)d_in[13], (const float*)d_in[19]};
    const int Ks[3] = {1024, 512, 256};
    const int Os[3] = {512, 256, 64};
    const int Zs[3] = {8, 16, 16};     // z-splits -> 1024 blocks each
    float* out = (float*)d_out;
    char* ws = (char*)d_ws;
    const size_t MB = (size_t)1 << 20;

    unsigned short* HbfX = (unsigned short*)(ws);             // 16 MB
    unsigned short* Hbf2 = (unsigned short*)(ws + 16 * MB);   // 8 MB
    unsigned short* Zt   = (unsigned short*)(ws + 24 * MB);   // 8 MB
    float*          Hacc = (float*)(ws + 32 * MB);            // 16 MB
    unsigned short* Wbf  = (unsigned short*)(ws + 48 * MB);   // 2 MB
    float* tv = (float*)(ws + 50 * MB);
    float* rv = tv + NN;
    float* dv = rv + NN;
    unsigned short* Abf = (unsigned short*)(ws + 51 * MB);    // 128 MB
    const bool useAbf = (ws_size >= 180 * MB);

    unsigned short* WbfL[3] = {Wbf, Wbf + 512 * 1024, Wbf + 512 * 1024 + 256 * 512};

    cvt_bf16<<<(NN * 1024) / 2048, 256, 0, stream>>>(X, HbfX);
    for (int L = 0; L < 3; ++L)
        cvt_bf16<<<(Os[L] * Ks[L]) / 2048, 256, 0, stream>>>(Wws[L], WbfL[L]);
    if (useAbf)
        cvt_bf16<<<(int)(((size_t)NN * NN) / 2048), 256, 0, stream>>>(A, Abf);

    const unsigned short* Hbf_in = HbfX;
    for (int L = 0; L < 3; ++L) {
        int K = Ks[L], O = Os[L];
        int zs = Zs[L];
        int kcount = NN / (zs * 32);
        proj_mfma<<<dim3(O / 64, NN / 128), 256, 0, stream>>>(
            Hbf_in, WbfL[L], Wbs[L], Zt, K, O);
        hipMemsetAsync(tv, 0, 96 * 1024, stream);          // tv, rv, dv
        tr_zt<<<dim3(NN / 256, O / 64), 256, 0, stream>>>(
            Zt, tws[L], tbs[L], rws[L], rbs[L], tv, rv);
        hipMemsetAsync(Hacc, 0, (size_t)NN * O * sizeof(float), stream);
        int gx = (O >= 256) ? O / 256 : 1;
        dim3 grid(gx, NN / 128, zs);
        if (useAbf) {
            if (O >= 256)
                attn_fused<256, unsigned short><<<grid, 256, 0, stream>>>(
                    Abf, Zt, tv, rv, Hacc, dv, O, kcount);
            else
                attn_fused<64, unsigned short><<<grid, 256, 0, stream>>>(
                    Abf, Zt, tv, rv, Hacc, dv, O, kcount);
        } else {
            if (O >= 256)
                attn_fused<256, float><<<grid, 256, 0, stream>>>(
                    A, Zt, tv, rv, Hacc, dv, O, kcount);
            else
                attn_fused<64, float><<<grid, 256, 0, stream>>>(
                    A, Zt, tv, rv, Hacc, dv, O, kcount);
        }
        float* outf = (L == 2) ? out : nullptr;
        unsigned short* outb = (L == 2) ? nullptr : Hbf2;
        norm_cvt<<<(NN / 256) * (O / 4), 256, 0, stream>>>(Hacc, dv, outf, outb, O);
        Hbf_in = Hbf2;
    }
}

// Round 3
// 849.115 us; speedup vs baseline: 1.1263x; 1.0839x over previous
//
#include <hip/hip_runtime.h>
#include <math.h>

#define NN 8192

typedef __attribute__((ext_vector_type(8))) short short8;
typedef __attribute__((ext_vector_type(4))) float f32x4;

__device__ __forceinline__ float bf2f(unsigned short u) {
    unsigned int x = ((unsigned int)u) << 16;
    return __builtin_bit_cast(float, x);
}
__device__ __forceinline__ unsigned int cvt_pk_bf16(float lo, float hi) {
    unsigned int r;
    asm("v_cvt_pk_bf16_f32 %0, %1, %2" : "=v"(r) : "v"(lo), "v"(hi));
    return r;
}
__device__ __forceinline__ float fast_sigexp(float x) {
    float s = __builtin_amdgcn_rcpf(1.0f + __expf(-x));
    return __expf(s);
}
__device__ __forceinline__ void gload16(const void* g, void* l) {
    __builtin_amdgcn_global_load_lds(
        (const __attribute__((address_space(1))) unsigned int*)g,
        (__attribute__((address_space(3))) unsigned int*)l, 16, 0, 0);
}

// ---------------- fp32 -> bf16 conversion ----------------
__global__ __launch_bounds__(256) void cvt_bf16(
    const float* __restrict__ src, unsigned short* __restrict__ dst)
{
    size_t idx = ((size_t)blockIdx.x * 256 + threadIdx.x) * 8;
    float4 a = *(const float4*)(src + idx);
    float4 b = *(const float4*)(src + idx + 4);
    uint4 o = { cvt_pk_bf16(a.x, a.y), cvt_pk_bf16(a.z, a.w),
                cvt_pk_bf16(b.x, b.y), cvt_pk_bf16(b.z, b.w) };
    *(uint4*)(dst + idx) = o;
}

// ---------------- raw 32B row loads + conversion helpers ----------------
template<typename AT> struct ARow;
template<> struct ARow<unsigned short> {
    struct Raw { uint4 a, b; };
    static __device__ __forceinline__ Raw ld(const unsigned short* p) {
        Raw r; r.a = ((const uint4*)p)[0]; r.b = ((const uint4*)p)[1]; return r;
    }
    static __device__ __forceinline__ void cvt(const Raw& r, float* d) {
        unsigned int wd[8] = {r.a.x, r.a.y, r.a.z, r.a.w, r.b.x, r.b.y, r.b.z, r.b.w};
        #pragma unroll
        for (int k = 0; k < 8; ++k) {
            d[2*k]   = __builtin_bit_cast(float, wd[k] << 16);
            d[2*k+1] = __builtin_bit_cast(float, wd[k] & 0xFFFF0000u);
        }
    }
};
template<> struct ARow<float> {
    struct Raw { float4 v[4]; };
    static __device__ __forceinline__ Raw ld(const float* p) {
        Raw r;
        r.v[0] = ((const float4*)p)[0]; r.v[1] = ((const float4*)p)[1];
        r.v[2] = ((const float4*)p)[2]; r.v[3] = ((const float4*)p)[3];
        return r;
    }
    static __device__ __forceinline__ void cvt(const Raw& r, float* d) {
        #pragma unroll
        for (int q = 0; q < 4; ++q) {
            d[4*q+0] = r.v[q].x; d[4*q+1] = r.v[q].y;
            d[4*q+2] = r.v[q].z; d[4*q+3] = r.v[q].w;
        }
    }
};
// f32 fallback staging of one 16-elem A-col chunk into bf16 LDS
struct AcStageF32 {
    static __device__ __forceinline__ void st(const ARow<float>::Raw& rw, unsigned short* dst) {
        float v[16];
        ARow<float>::cvt(rw, v);
        unsigned int d[8];
        #pragma unroll
        for (int k = 0; k < 8; ++k) d[k] = cvt_pk_bf16(v[2*k], v[2*k+1]);
        uint4 s0 = {d[0], d[1], d[2], d[3]};
        uint4 s1 = {d[4], d[5], d[6], d[7]};
        ((uint4*)dst)[0] = s0;
        ((uint4*)dst)[1] = s1;
    }
};

// ---------------- projection GEMM (bf16 MFMA): Zt[o][i] = relu(H@W^T + b) ----------------
// double-buffered LDS, prefetch-at-top, ONE barrier per K-step (round-1 verified)
__global__ __launch_bounds__(256) void proj_mfma(
    const unsigned short* __restrict__ Hbf,
    const unsigned short* __restrict__ Wbf,
    const float* __restrict__ bias,
    unsigned short* __restrict__ Zt,
    int K, int O)
{
    constexpr int MT = 4, NT = 2;
    __shared__ unsigned short smem[12288];   // 2 bufs x (As 4096 + Bs 2048) shorts
    const int tid = threadIdx.x;
    const int w = tid >> 6;
    const int lane = tid & 63;
    const int quad = lane >> 4;
    const int m16 = lane & 15;
    const int i0 = blockIdx.y * 128;
    const int o0 = blockIdx.x * 64;
    const int wm = w & 1;
    const int wn = w >> 1;

    const char* gpa[2]; unsigned int loa[2];
    #pragma unroll
    for (int n = 0; n < 2; ++n) {
        int o16 = n * 256 + w * 64 + lane;
        int row = o16 >> 2, ch = o16 & 3;
        int sc = ch ^ ((row >> 1) & 3);
        gpa[n] = (const char*)(Hbf + (size_t)(i0 + row) * K) + sc * 16;
        loa[n] = n * 4096 + w * 1024 + lane * 16;
    }
    const char* gpb; unsigned int lob_;
    {
        int o16 = w * 64 + lane;
        int row = o16 >> 2, ch = o16 & 3;
        int sc = ch ^ ((row >> 1) & 3);
        gpb = (const char*)(Wbf + (size_t)(o0 + row) * K) + sc * 16;
        lob_ = 8192 + w * 1024 + lane * 16;
    }
    int aoff[MT], boff[NT];
    #pragma unroll
    for (int mt = 0; mt < MT; ++mt) {
        int row = wm * 64 + mt * 16 + m16;
        int sc = quad ^ ((row >> 1) & 3);
        aoff[mt] = row * 32 + sc * 8;
    }
    #pragma unroll
    for (int nt = 0; nt < NT; ++nt) {
        int row = wn * 32 + nt * 16 + m16;
        int sc = quad ^ ((row >> 1) & 3);
        boff[nt] = 4096 + row * 32 + sc * 8;
    }
    f32x4 acc[MT][NT];
    #pragma unroll
    for (int mt = 0; mt < MT; ++mt)
        #pragma unroll
        for (int nt = 0; nt < NT; ++nt)
            acc[mt][nt] = (f32x4){0.f, 0.f, 0.f, 0.f};

    gload16(gpa[0], (char*)smem + loa[0]);
    gload16(gpa[1], (char*)smem + loa[1]);
    gload16(gpb,    (char*)smem + lob_);
    __syncthreads();

    const int nk = K >> 5;
    for (int kk = 0; kk < nk; ++kk) {
        const int s = kk & 1;
        if (kk + 1 < nk) {
            char* dst = (char*)smem + (s ^ 1) * 12288;
            gload16(gpa[0] + (size_t)(kk + 1) * 64, dst + loa[0]);
            gload16(gpa[1] + (size_t)(kk + 1) * 64, dst + loa[1]);
            gload16(gpb    + (size_t)(kk + 1) * 64, dst + lob_);
        }
        const unsigned short* buf = smem + s * 6144;
        short8 af[MT], bf_[NT];
        #pragma unroll
        for (int mt = 0; mt < MT; ++mt) af[mt] = *(const short8*)(buf + aoff[mt]);
        #pragma unroll
        for (int nt = 0; nt < NT; ++nt) bf_[nt] = *(const short8*)(buf + boff[nt]);
        __builtin_amdgcn_s_setprio(1);
        #pragma unroll
        for (int mt = 0; mt < MT; ++mt)
            #pragma unroll
            for (int nt = 0; nt < NT; ++nt)
                acc[mt][nt] = __builtin_amdgcn_mfma_f32_16x16x32_bf16(
                    af[mt], bf_[nt], acc[mt][nt], 0, 0, 0);
        __builtin_amdgcn_s_setprio(0);
        __syncthreads();
    }
    #pragma unroll
    for (int nt = 0; nt < NT; ++nt) {
        int ol = wn * 32 + nt * 16 + m16;
        float bv = bias[o0 + ol];
        #pragma unroll
        for (int mt = 0; mt < MT; ++mt) {
            int il = wm * 64 + mt * 16 + quad * 4;
            float f0 = fmaxf(acc[mt][nt][0] + bv, 0.f);
            float f1 = fmaxf(acc[mt][nt][1] + bv, 0.f);
            float f2 = fmaxf(acc[mt][nt][2] + bv, 0.f);
            float f3 = fmaxf(acc[mt][nt][3] + bv, 0.f);
            uint2 pk = { cvt_pk_bf16(f0, f1), cvt_pk_bf16(f2, f3) };
            *(uint2*)&smem[ol * 136 + il] = pk;
        }
    }
    __syncthreads();
    #pragma unroll
    for (int c = 0; c < 4; ++c) {
        int cc = c * 256 + tid;
        int ol = cc >> 4;
        int ic = (cc & 15) << 3;
        *(uint4*)(Zt + (size_t)(o0 + ol) * NN + i0 + ic) = *(const uint4*)&smem[ol * 136 + ic];
    }
}

// ---------------- t,r: column-split atomic dots over Zt ----------------
__global__ __launch_bounds__(256) void tr_zt(
    const unsigned short* __restrict__ Zt,
    const float* __restrict__ tw, const float* __restrict__ tb,
    const float* __restrict__ rw, const float* __restrict__ rb,
    float* __restrict__ t, float* __restrict__ r)
{
    const int i  = blockIdx.x * 256 + threadIdx.x;
    const int c0 = blockIdx.y * 64;
    float at = 0.f, ar = 0.f;
    for (int c = c0; c < c0 + 64; ++c) {
        float z = bf2f(Zt[(size_t)c * NN + i]);
        at = fmaf(z, tw[c], at);
        ar = fmaf(z, rw[c], ar);
    }
    if (blockIdx.y == 0) { at += tb[0]; ar += rb[0]; }
    atomicAdd(t + i, at);
    atomicAdd(r + i, ar);
}

// ---------------- fused attention: ONE __syncthreads per j-block ----------------
// body(kk):  P-phase (reads Ac[b], regs; writes As[b])
//            __syncthreads()      // the ONLY sync; full vm+lgkm drain
//            issue Bs(kk+1)->Bs[b^1], Ac(kk+2)->Ac[b], regs(kk+1)
//            MFMA As[b] x Bs[b]   (setprio-wrapped)
// Cover: a gload issued at segment start is drained at the NEXT sync, after
// MFMA(kk)+P(kk+1) -- ~full iteration. Hazards (each crosses >=1 full sync):
//   As[b] W(P,kk)->R(MFMA,kk): sync(kk). As[b] R(MFMA,kk)->W(P,kk+2): sync(kk+1).
//   Bs[b^1] W(G,kk+1 post-sync(kk)) vs R(MFMA,kk-1): reads drained at sync(kk).
//   Ac[b]  W(G,kk+2 post-sync(kk)) vs R(P,kk): reads drained at sync(kk);
//          consumed P(kk+2) after sync(kk+1) which drains the gload.
template<int BN, typename AT>
__global__ __launch_bounds__(256) void attn_fused(
    const AT* __restrict__ A,
    const unsigned short* __restrict__ Zt,   // [O][NN] bf16
    const float* __restrict__ t, const float* __restrict__ r,
    float* __restrict__ Hacc, float* __restrict__ denom,
    int O, int kcount)
{
    constexpr bool BFA = (sizeof(AT) == 2);
    constexpr int BM = 128, BK = 32;
    constexpr int MT = 4;
    constexpr int NT = BN / 32;
    constexpr int NB = (BN * BK * 2) / 4096;
    constexpr int BNK = BN * BK;
    constexpr size_t ACB = (size_t)BK * NN * sizeof(AT);   // A bytes per j-block
    __shared__ unsigned short As[2][BM * BK];    // P tiles (double-buffered)
    __shared__ unsigned short Bs[2][BNK];        // Zt tiles (double-buffered)
    __shared__ unsigned short Ac[2][BK * BM];    // A-col tiles (double-buffered, 2-ahead)
    const int tid  = threadIdx.x;
    const int w    = tid >> 6;
    const int lane = tid & 63;
    const int quad = lane >> 4;
    const int m16  = lane & 15;
    const int i0 = blockIdx.y * BM;
    const int c0 = blockIdx.x * BN;
    const int wm = w & 1;
    const int wn = w >> 1;
    const int jbase = blockIdx.z * kcount * BK;
    const bool x0 = (blockIdx.x == 0);

    // compute-role: thread owns (row ci, 16-j half jh)
    const int ci = tid >> 1;
    const int jh = tid & 1;
    const float ri = r[i0 + ci];
    const int si = (ci >> 1) & 3;
    const int aswo0 = ci * 32 + (((jh * 2)    ) ^ si) * 8;
    const int aswo1 = ci * 32 + (((jh * 2) + 1) ^ si) * 8;
    const int acrd = jh * 16 * BM + (ci ^ (jh << 5));   // swizzled Ac read base

    // Bs gload pointers
    const char* gpb[NB]; unsigned int lob[NB];
    #pragma unroll
    for (int n = 0; n < NB; ++n) {
        int o16 = n * 256 + w * 64 + lane;
        int row = o16 >> 2, ch = o16 & 3;
        int sc = ch ^ ((row >> 1) & 3);
        gpb[n] = (const char*)Zt + ((size_t)(c0 + row) * NN + jbase) * 2 + sc * 16;
        lob[n] = n * 4096 + w * 1024 + lane * 16;
    }
    // Ac staging: gload16-direct (bf16) or reg-staged (f32 fallback)
    const char* gpac[2] = {nullptr, nullptr};
    unsigned int loac[2] = {0, 0};
    const float* astage = nullptr;
    int acw_off = 0;
    if constexpr (BFA) {
        #pragma unroll
        for (int n = 0; n < 2; ++n) {
            int o16 = n * 256 + tid;
            int row = o16 >> 4;
            int c16 = (o16 & 15) ^ ((row >> 4) << 2);   // pre-swizzled global source
            gpac[n] = (const char*)(A + (size_t)(jbase + row) * NN + i0 + c16 * 8);
            loac[n] = (unsigned int)(o16 * 16);
        }
    } else {
        const int sj = tid >> 3;
        const int sm = tid & 7;
        astage = (const float*)A + (size_t)(jbase + sj) * NN + i0 + sm * 16;
        acw_off = sj * BM + (((sm * 2) ^ ((sj >> 4) << 2)) * 8);
    }

    int aoff[MT], boff[NT];
    #pragma unroll
    for (int mt = 0; mt < MT; ++mt) {
        int row = wm * 64 + mt * 16 + m16;
        int sc = quad ^ ((row >> 1) & 3);
        aoff[mt] = row * 32 + sc * 8;
    }
    #pragma unroll
    for (int nt = 0; nt < NT; ++nt) {
        int row = wn * (BN / 2) + nt * 16 + m16;
        int sc = quad ^ ((row >> 1) & 3);
        boff[nt] = row * 32 + sc * 8;
    }

    f32x4 acc[MT][NT];
    #pragma unroll
    for (int mt = 0; mt < MT; ++mt)
        #pragma unroll
        for (int nt = 0; nt < NT; ++nt)
            acc[mt][nt] = (f32x4){0.f, 0.f, 0.f, 0.f};

    const AT* arow = A + (size_t)(i0 + ci) * NN + jbase + jh * 16;
    const float* tptr = t + jbase + jh * 16;

    // prologue: Bs(0)->Bs[0]; Ac(0)->Ac[0]; Ac(1)->Ac[1]; regs(0); full drain
    #pragma unroll
    for (int n = 0; n < NB; ++n)
        gload16(gpb[n], (char*)(Bs[0]) + lob[n]);
    if constexpr (BFA) {
        gload16(gpac[0], (char*)(Ac[0]) + loac[0]);
        gload16(gpac[1], (char*)(Ac[0]) + loac[1]);
        if (kcount > 1) {
            gload16(gpac[0] + ACB, (char*)(Ac[1]) + loac[0]);
            gload16(gpac[1] + ACB, (char*)(Ac[1]) + loac[1]);
        }
    } else {
        AcStageF32::st(ARow<float>::ld(astage), &Ac[0][0] + acw_off);
        if (kcount > 1)
            AcStageF32::st(ARow<float>::ld(astage + (size_t)BK * NN), &Ac[1][0] + acw_off);
    }
    typename ARow<AT>::Raw avr = ARow<AT>::ld(arow);
    float4 tvr0 = ((const float4*)tptr)[0];
    float4 tvr1 = ((const float4*)tptr)[1];
    float4 tvr2 = ((const float4*)tptr)[2];
    float4 tvr3 = ((const float4*)tptr)[3];
    __syncthreads();

    float rsum = 0.f;
    for (int kk = 0; kk < kcount; ++kk) {
        const int b = kk & 1;
        // ---- P-phase: p -> As[b] (reads Ac[b] + regs) ----
        float av[16];
        ARow<AT>::cvt(avr, av);
        float tf[16] = {tvr0.x, tvr0.y, tvr0.z, tvr0.w,
                        tvr1.x, tvr1.y, tvr1.z, tvr1.w,
                        tvr2.x, tvr2.y, tvr2.z, tvr2.w,
                        tvr3.x, tvr3.y, tvr3.z, tvr3.w};
        const unsigned short* acb = &Ac[b][0] + acrd;
        unsigned int wd[8];
        #pragma unroll
        for (int q = 0; q < 8; ++q) {
            float j0 = bf2f(acb[(2 * q) * BM]);
            float j1 = bf2f(acb[(2 * q + 1) * BM]);
            float x0v = fmaf(av[2 * q],     tf[2 * q],     j0 * ri);
            float x1v = fmaf(av[2 * q + 1], tf[2 * q + 1], j1 * ri);
            float p0 = fast_sigexp(x0v);
            float p1 = fast_sigexp(x1v);
            if (x0) { rsum += p0; rsum += p1; }
            wd[q] = cvt_pk_bf16(p0, p1);
        }
        {
            uint4 s0 = {wd[0], wd[1], wd[2], wd[3]};
            uint4 s1 = {wd[4], wd[5], wd[6], wd[7]};
            *(uint4*)(&As[b][0] + aswo0) = s0;
            *(uint4*)(&As[b][0] + aswo1) = s1;
        }
        __syncthreads();   // THE sync: As[b] visible; G(kk)/regs drained (full-iter cover)
        // ---- post-sync issues (drained at sync(kk+1)) ----
        if (kk + 1 < kcount) {
            #pragma unroll
            for (int n = 0; n < NB; ++n)
                gload16(gpb[n] + (size_t)(kk + 1) * 64, (char*)(Bs[b ^ 1]) + lob[n]);
        }
        if constexpr (BFA) {
            if (kk + 2 < kcount) {
                gload16(gpac[0] + (size_t)(kk + 2) * ACB, (char*)(Ac[b]) + loac[0]);
                gload16(gpac[1] + (size_t)(kk + 2) * ACB, (char*)(Ac[b]) + loac[1]);
            }
        } else {
            if (kk + 2 < kcount)
                AcStageF32::st(ARow<float>::ld(astage + (size_t)(kk + 2) * BK * NN),
                               &Ac[b][0] + acw_off);
        }
        if (kk + 1 < kcount) {
            avr = ARow<AT>::ld(arow + (size_t)(kk + 1) * BK);
            const float* tp = tptr + (kk + 1) * BK;
            tvr0 = ((const float4*)tp)[0];
            tvr1 = ((const float4*)tp)[1];
            tvr2 = ((const float4*)tp)[2];
            tvr3 = ((const float4*)tp)[3];
        }
        // ---- MFMA phase ----
        {
            const unsigned short* asb = &As[b][0];
            const unsigned short* bsb = Bs[b];
            short8 af[MT], bf_[NT];
            #pragma unroll
            for (int mt = 0; mt < MT; ++mt) af[mt] = *(const short8*)(asb + aoff[mt]);
            #pragma unroll
            for (int nt = 0; nt < NT; ++nt) bf_[nt] = *(const short8*)(bsb + boff[nt]);
            __builtin_amdgcn_s_setprio(1);
            #pragma unroll
            for (int mt = 0; mt < MT; ++mt)
                #pragma unroll
                for (int nt = 0; nt < NT; ++nt)
                    acc[mt][nt] = __builtin_amdgcn_mfma_f32_16x16x32_bf16(
                        af[mt], bf_[nt], acc[mt][nt], 0, 0, 0);
            __builtin_amdgcn_s_setprio(0);
        }
    }

    // denom accumulation (unquantized fp32 row sums), x==0 blocks only
    rsum += __shfl_xor(rsum, 1);
    if (jh == 0 && x0)
        atomicAdd(denom + i0 + ci, rsum);

    // unnormalized atomic output
    const int colb = c0 + wn * (BN / 2) + m16;
    #pragma unroll
    for (int mt = 0; mt < MT; ++mt) {
        int rowb = i0 + wm * 64 + mt * 16 + quad * 4;
        #pragma unroll
        for (int rg = 0; rg < 4; ++rg) {
            float* orow = Hacc + (size_t)(rowb + rg) * O + colb;
            #pragma unroll
            for (int nt = 0; nt < NT; ++nt)
                atomicAdd(orow + nt * 16, acc[mt][nt][rg]);
        }
    }
}

// ---------------- normalize + emit (f32 out or bf16 next-layer input) ----------------
__global__ __launch_bounds__(256) void norm_cvt(
    const float* __restrict__ Hacc, const float* __restrict__ denom,
    float* __restrict__ outf, unsigned short* __restrict__ outb, int O)
{
    const int gid = blockIdx.x * 256 + threadIdx.x;
    const int n4 = O >> 2;
    const int i = gid / n4;
    const int c = (gid % n4) << 2;
    float inv = __builtin_amdgcn_rcpf(denom[i]);
    float4 v = *(const float4*)(Hacc + (size_t)i * O + c);
    v.x *= inv; v.y *= inv; v.z *= inv; v.w *= inv;
    if (outf) {
        *(float4*)(outf + (size_t)i * O + c) = v;
    } else {
        uint2 o = { cvt_pk_bf16(v.x, v.y), cvt_pk_bf16(v.z, v.w) };
        *(uint2*)(outb + (size_t)i * O + c) = o;
    }
}

// ---------------- host ----------------
extern "C" void kernel_launch(void* const* d_in, const int* in_sizes, int n_in,
                              void* d_out, int out_size, void* d_ws, size_t ws_size,
                              hipStream_t stream)
{
    (void)in_sizes; (void)n_in; (void)out_size;
    const float* X = (const float*)d_in[0];
    const float* A = (const float*)d_in[1];
    const float* Wws[3] = {(const float*)d_in[2],  (const float*)d_in[8],  (const float*)d_in[14]};
    const float* Wbs[3] = {(const float*)d_in[3],  (const float*)d_in[9],  (const float*)d_in[15]};
    const float* tws[3] = {(const float*)d_in[4],  (const float*)d_in[10], (const float*)d_in[16]};
    const float* tbs[3] = {(const float*)d_in[5],  (const float*)d_in[11], (const float*)d_in[17]};
    const float* rws[3] = {(const float*)d_in[6],  (const float*)d_in[12], (const float*)d_in[18]};
    const float* rbs[3] = {(const float*)d_in[7],  (const float*)d_in[13], (const float*)d_in[19]};
    const int Ks[3] = {1024, 512, 256};
    const int Os[3] = {512, 256, 64};
    const int Zs[3] = {4, 8, 8};       // z-splits -> 512 blocks each (2 resident/CU)
    float* out = (float*)d_out;
    char* ws = (char*)d_ws;
    const size_t MB = (size_t)1 << 20;

    unsigned short* HbfX = (unsigned short*)(ws);             // 16 MB
    unsigned short* Hbf2 = (unsigned short*)(ws + 16 * MB);   // 8 MB
    unsigned short* Zt   = (unsigned short*)(ws + 24 * MB);   // 8 MB
    float*          Hacc = (float*)(ws + 32 * MB);            // 16 MB
    unsigned short* Wbf  = (unsigned short*)(ws + 48 * MB);   // 2 MB
    float* tv = (float*)(ws + 50 * MB);
    float* rv = tv + NN;
    float* dv = rv + NN;
    unsigned short* Abf = (unsigned short*)(ws + 51 * MB);    // 128 MB
    const bool useAbf = (ws_size >= 180 * MB);

    unsigned short* WbfL[3] = {Wbf, Wbf + 512 * 1024, Wbf + 512 * 1024 + 256 * 512};

    cvt_bf16<<<(NN * 1024) / 2048, 256, 0, stream>>>(X, HbfX);
    for (int L = 0; L < 3; ++L)
        cvt_bf16<<<(Os[L] * Ks[L]) / 2048, 256, 0, stream>>>(Wws[L], WbfL[L]);
    if (useAbf)
        cvt_bf16<<<(int)(((size_t)NN * NN) / 2048), 256, 0, stream>>>(A, Abf);

    const unsigned short* Hbf_in = HbfX;
    for (int L = 0; L < 3; ++L) {
        int K = Ks[L], O = Os[L];
        int zs = Zs[L];
        int kcount = NN / (zs * 32);
        proj_mfma<<<dim3(O / 64, NN / 128), 256, 0, stream>>>(
            Hbf_in, WbfL[L], Wbs[L], Zt, K, O);
        hipMemsetAsync(tv, 0, 96 * 1024, stream);          // tv, rv, dv
        tr_zt<<<dim3(NN / 256, O / 64), 256, 0, stream>>>(
            Zt, tws[L], tbs[L], rws[L], rbs[L], tv, rv);
        hipMemsetAsync(Hacc, 0, (size_t)NN * O * sizeof(float), stream);
        int gx = (O >= 256) ? O / 256 : 1;
        dim3 grid(gx, NN / 128, zs);
        if (useAbf) {
            if (O >= 256)
                attn_fused<256, unsigned short><<<grid, 256, 0, stream>>>(
                    Abf, Zt, tv, rv, Hacc, dv, O, kcount);
            else
                attn_fused<64, unsigned short><<<grid, 256, 0, stream>>>(
                    Abf, Zt, tv, rv, Hacc, dv, O, kcount);
        } else {
            if (O >= 256)
                attn_fused<256, float><<<grid, 256, 0, stream>>>(
                    A, Zt, tv, rv, Hacc, dv, O, kcount);
            else
                attn_fused<64, float><<<grid, 256, 0, stream>>>(
                    A, Zt, tv, rv, Hacc, dv, O, kcount);
        }
        float* outf = (L == 2) ? out : nullptr;
        unsigned short* outb = (L == 2) ? nullptr : Hbf2;
        norm_cvt<<<(NN / 256) * (O / 4), 256, 0, stream>>>(Hacc, dv, outf, outb, O);
        Hbf_in = Hbf2;
    }
}